// Round 2
// baseline (426.473 us; speedup 1.0000x reference)
//
#include <hip/hip_runtime.h>
#include <hip/hip_bf16.h>
#include <hip/hip_fp16.h>

#define N_NODES 100000
#define R_REL   7
#define E_EDGES 1600000
#define EDIM    16
#define KTOT    640    // 448 msg + 64 self + 112 F + 7 sw + 9 pad  (B layout, K dim)
#define KSTR    648    // A-tile LDS row stride: 1296B = 324 dw, 324%32=4 -> 2-way (free)
#define CAP     56     // slots per node; P(deg>55 | Binom(1.6M,1e-5)) ~ 4e-10

typedef __bf16 bf16_t;
typedef bf16_t bf16x8 __attribute__((ext_vector_type(8)));
typedef bf16_t bf16x4 __attribute__((ext_vector_type(4)));
typedef float  f32x4  __attribute__((ext_vector_type(4)));
typedef unsigned long long u64;

#define RFL(v) __builtin_amdgcn_readfirstlane(v)
#define RL(v, l) __builtin_amdgcn_readlane(v, l)

// ---------------- fused prep + scatter (cnt zeroed by hipMemsetAsync) -------
// record (8B): u0 = src(17b) | rel(3b)<<17 | e[0:12)<<20
//              u1 = e[12:21) | (f32(w) & 0xFFFFFE00)
// 8 edges/thread: 8 independent atomic->store chains in flight (latency-bound
// pass; was 4). Record stores nontemporal: skip write-allocate line fetch.

__global__ __launch_bounds__(256) void k_pre(
    const float* __restrict__ x, const int* __restrict__ el,
    const float* __restrict__ wgt,
    const float* __restrict__ W_lin, const float* __restrict__ W_self,
    const float* __restrict__ W_edge, const float* __restrict__ b_edge,
    int* __restrict__ cnt, bf16_t* __restrict__ xb, bf16_t* __restrict__ Bp,
    u64* __restrict__ recs8)
{
    const int t = blockIdx.x * 256 + threadIdx.x;

    // ---- x -> bf16, 16 floats per thread (400000 threads) ----
    if (t < (N_NODES * 64) / 16) {
        const float4* xp = (const float4*)(x + (size_t)t * 16);
        float4 v0 = xp[0], v1 = xp[1], v2 = xp[2], v3 = xp[3];
        bf16x8 o0 = {(bf16_t)v0.x, (bf16_t)v0.y, (bf16_t)v0.z, (bf16_t)v0.w,
                     (bf16_t)v1.x, (bf16_t)v1.y, (bf16_t)v1.z, (bf16_t)v1.w};
        bf16x8 o1 = {(bf16_t)v2.x, (bf16_t)v2.y, (bf16_t)v2.z, (bf16_t)v2.w,
                     (bf16_t)v3.x, (bf16_t)v3.y, (bf16_t)v3.z, (bf16_t)v3.w};
        *(bf16x8*)(xb + (size_t)t * 16)     = o0;
        *(bf16x8*)(xb + (size_t)t * 16 + 8) = o1;
    }

    // ---- pack B (40960 threads) ----
    // B[k][j]: k<448 W_lin[j][k]; 448..511 W_self; 512..623 (W_lin_r@W_edge);
    // 624..630 (W_lin_r@b_edge); 631..639 zero.  Bp[((k/8)*64 + j)*8 + (k%8)]
    if (t < KTOT * 64) {
        int k = t >> 6;
        int j = t & 63;
        float v;
        if (k < 448) {
            v = W_lin[j * 448 + k];
        } else if (k < 512) {
            v = W_self[j * 64 + (k - 448)];
        } else if (k < 624) {
            int r = (k - 512) >> 4, kk = (k - 512) & 15;
            float sacc = 0.f;
            for (int d = 0; d < 64; d++)
                sacc = fmaf(W_lin[j * 448 + r * 64 + d], W_edge[d * 16 + kk], sacc);
            v = sacc;
        } else if (k < 631) {
            int r = k - 624;
            float sacc = 0.f;
            for (int d = 0; d < 64; d++)
                sacc = fmaf(W_lin[j * 448 + r * 64 + d], b_edge[d], sacc);
            v = sacc;
        } else {
            v = 0.f;
        }
        Bp[((k >> 3) * 64 + j) * 8 + (k & 7)] = (bf16_t)v;
    }

    // ---- scatter: 8 edges / thread, int4-coalesced (200000 threads) ----
    if (t < E_EDGES / 8) {
        const int4* ep = (const int4*)(el + (size_t)t * 24);  // t*96B, 16B-aligned
        int4 q0 = ep[0], q1 = ep[1], q2 = ep[2];
        int4 q3 = ep[3], q4 = ep[4], q5 = ep[5];
        float4 wa = *(const float4*)(wgt + (size_t)t * 8);
        float4 wc = *(const float4*)(wgt + (size_t)t * 8 + 4);
        const int e = t * 8;
        const int srcs[8] = {q0.x, q0.w, q1.z, q2.y, q3.x, q3.w, q4.z, q5.y};
        const int dsts[8] = {q0.y, q1.x, q1.w, q2.z, q3.y, q4.x, q4.w, q5.z};
        const int rels[8] = {q0.z, q1.y, q2.x, q2.w, q3.z, q4.y, q5.x, q5.w};
        const float ws[8] = {wa.x, wa.y, wa.z, wa.w, wc.x, wc.y, wc.z, wc.w};
        int slot[8];
#pragma unroll
        for (int i = 0; i < 8; i++)
            slot[i] = atomicAdd(&cnt[dsts[i]], 1);
#pragma unroll
        for (int i = 0; i < 8; i++) {
            unsigned u0 = (unsigned)srcs[i] | ((unsigned)rels[i] << 17)
                        | ((unsigned)((e + i) & 0xFFF) << 20);
            unsigned u1 = ((unsigned)(e + i) >> 12)
                        | (__float_as_uint(ws[i]) & 0xFFFFFE00u);
            __builtin_nontemporal_store(((u64)u1 << 32) | u0,
                &recs8[(size_t)dsts[i] * CAP + slot[i]]);
        }
    }
}

// ---------------- fused gather/segment-sum + MFMA GEMM ----------------------
// block = 1024 thr (16 waves) = 16 nodes, ONE NODE PER WAVE: quarters the
// per-wave serial latency chain vs 4-nodes-per-wave, and occupancy goes to
// 32 waves/CU (2 blocks x 16 waves). Window read predicated by lane<m.
// Stage 2 (MFMA over K=640, verified) runs on waves 0-3 after the barrier.

__global__ __launch_bounds__(1024) void k_main(
    const bf16_t* __restrict__ xb, const float* __restrict__ ef,
    const float* __restrict__ b_lin, const float* __restrict__ b_self,
    const int* __restrict__ cnt, const u64* __restrict__ recs8,
    const bf16_t* __restrict__ Bp, float* __restrict__ out)
{
    __shared__ __align__(16) bf16_t A[16 * KSTR];  // 20.25 KB, padded stride
    const int wave = threadIdx.x >> 6;
    const int lane = threadIdx.x & 63;
    const int lef  = lane & 15;
    const int nodeBase = blockIdx.x * 16;
    const int n = nodeBase + wave;

    const int m = min(cnt[n], CAP);
    u64 rv = 0;
    if (lane < m) rv = recs8[(size_t)n * CAP + lane];
    const bf16_t svv = xb[n * 64 + lane];

    bf16_t* Ar = A + wave * KSTR;
    Ar[448 + lane] = svv;                         // self-term slot
    if (lane < 9) Ar[631 + lane] = (bf16_t)0.f;   // pad cols

    const unsigned u0v = (unsigned)rv;
    const unsigned u1v = (unsigned)(rv >> 32);
    const int  relv  = (u0v >> 17) & 7;
    const bool valid = lane < m;

    for (int r = 0; r < R_REL; r++) {
        u64 mr = __ballot(valid && (relv == r));
        float a = 0.f, F = 0.f, s = 0.f;
        while (mr) {
            int i0 = __builtin_ctzll(mr); mr &= mr - 1;
            int i1 = i0; bool two = false, more = false;
            if (mr) { i1 = __builtin_ctzll(mr); mr &= mr - 1;
                      two = true; more = (mr != 0); }
            unsigned a0 = RL(u0v, i0), b0 = RL(u1v, i0);
            unsigned a1 = RL(u0v, i1), b1 = RL(u1v, i1);
            int src0 = a0 & 0x1FFFF, src1 = a1 & 0x1FFFF;
            int e0 = (a0 >> 20) | ((b0 & 0x1FF) << 12);
            int e1 = (a1 >> 20) | ((b1 & 0x1FF) << 12);
            float w0 = __uint_as_float(b0 & 0xFFFFFE00u);
            float w1 = two ? __uint_as_float(b1 & 0xFFFFFE00u) : 0.f;
            float xv0 = (float)xb[src0 * 64 + lane];
            float xv1 = (float)xb[src1 * 64 + lane];
            float ev0 = ef[e0 * EDIM + lef];
            float ev1 = ef[e1 * EDIM + lef];
            if (more) {  // wave-uniform: >=3 records in this group
                int i2 = __builtin_ctzll(mr); mr &= mr - 1;
                int i3 = i2; bool four = false;
                if (mr) { i3 = __builtin_ctzll(mr); mr &= mr - 1; four = true; }
                unsigned a2 = RL(u0v, i2), b2 = RL(u1v, i2);
                unsigned a3 = RL(u0v, i3), b3 = RL(u1v, i3);
                int src2 = a2 & 0x1FFFF, src3 = a3 & 0x1FFFF;
                int e2 = (a2 >> 20) | ((b2 & 0x1FF) << 12);
                int e3 = (a3 >> 20) | ((b3 & 0x1FF) << 12);
                float w2 = __uint_as_float(b2 & 0xFFFFFE00u);
                float w3 = four ? __uint_as_float(b3 & 0xFFFFFE00u) : 0.f;
                float xv2 = (float)xb[src2 * 64 + lane];
                float xv3 = (float)xb[src3 * 64 + lane];
                float ev2 = ef[e2 * EDIM + lef];
                float ev3 = ef[e3 * EDIM + lef];
                a = fmaf(w2, xv2, a); F = fmaf(w2, ev2, F); s += w2;
                a = fmaf(w3, xv3, a); F = fmaf(w3, ev3, F); s += w3;
            }
            a = fmaf(w0, xv0, a); F = fmaf(w0, ev0, F); s += w0;
            a = fmaf(w1, xv1, a); F = fmaf(w1, ev1, F); s += w1;
        }
        // one flush per relation (covers empty rels with zeros)
        Ar[r * 64 + lane] = (bf16_t)a;
        if (lane < EDIM) Ar[512 + r * EDIM + lane] = (bf16_t)F;
        if (lane == 0)   Ar[624 + r] = (bf16_t)s;
    }
    __syncthreads();

    // stage 2: MFMA over K=640 on waves 0-3 (A stride padded to KSTR)
    if (wave < 4) {
        const int quad = lane >> 4;
        const int l15  = lane & 15;
        f32x4 c = {0.f, 0.f, 0.f, 0.f};
#pragma unroll
        for (int s2i = 0; s2i < KTOT / 32; s2i++) {
            bf16x8 av = *(const bf16x8*)(A + l15 * KSTR + s2i * 32 + quad * 8);
            bf16x8 bv = *(const bf16x8*)(Bp + (((s2i * 4 + quad) * 64) + wave * 16 + l15) * 8);
            c = __builtin_amdgcn_mfma_f32_16x16x32_bf16(av, bv, c, 0, 0, 0);
        }
        const int j = wave * 16 + l15;
        const float bias = b_lin[j] + b_self[j];
#pragma unroll
        for (int q = 0; q < 4; q++) {
            const int nn = nodeBase + quad * 4 + q;
            float v = c[q] + bias;
            out[nn * 64 + j] = v > 0.f ? v : 0.f;
        }
    }
}

// ---------------- launch ----------------------------------------------------

extern "C" void kernel_launch(void* const* d_in, const int* in_sizes, int n_in,
                              void* d_out, int out_size, void* d_ws, size_t ws_size,
                              hipStream_t stream) {
    const float* x      = (const float*)d_in[0];
    const int*   el     = (const int*)  d_in[1];
    const float* wgt    = (const float*)d_in[2];
    const float* ef     = (const float*)d_in[3];
    const float* W_lin  = (const float*)d_in[4];
    const float* b_lin  = (const float*)d_in[5];
    const float* W_self = (const float*)d_in[6];
    const float* b_self = (const float*)d_in[7];
    const float* W_edge = (const float*)d_in[8];
    const float* b_edge = (const float*)d_in[9];
    float* out = (float*)d_out;

    // workspace: recs8(44.8M) | cnt(0.4M) | xb(12.8M) | Bp(80K)  ~58.1 MB
    u64*    recs8 = (u64*)d_ws;
    int*    cnt   = (int*)(recs8 + (size_t)N_NODES * CAP);
    bf16_t* xb    = (bf16_t*)(cnt + N_NODES);
    bf16_t* Bp    = xb + (size_t)N_NODES * 64;

    hipMemsetAsync(cnt, 0, N_NODES * sizeof(int), stream);
    k_pre <<<1563, 256, 0, stream>>>(x, el, wgt, W_lin, W_self, W_edge, b_edge,
                                     cnt, xb, Bp, recs8);
    k_main<<<N_NODES / 16, 1024, 0, stream>>>(xb, ef, b_lin, b_self,
                                              cnt, recs8, Bp, out);
}

// Round 3
// 378.283 us; speedup vs baseline: 1.1274x; 1.1274x over previous
//
#include <hip/hip_runtime.h>
#include <hip/hip_bf16.h>
#include <hip/hip_fp16.h>

#define N_NODES 100000
#define R_REL   7
#define E_EDGES 1600000
#define EDIM    16
#define KTOT    640    // 448 msg + 64 self + 112 F + 7 sw + 9 pad  (B layout, K dim)
#define KSTR    648    // A-tile LDS row stride: 1296B = 324 dw, 324%32=4 -> 2-way (free)
#define CAP     56     // slots per node; P(deg>55 | Binom(1.6M,1e-5)) ~ 4e-10
#define CSTR    16     // cnt stride in ints: one counter per 64B line (atomic RMW
                       // serializes per line at the service point; dense cnt had
                       // 16 ctr/line x deg 16 = 256 RMW/line -> the ~140us floor)

typedef __bf16 bf16_t;
typedef bf16_t bf16x8 __attribute__((ext_vector_type(8)));
typedef bf16_t bf16x4 __attribute__((ext_vector_type(4)));
typedef float  f32x4  __attribute__((ext_vector_type(4)));
typedef unsigned long long u64;

#define RFL(v) __builtin_amdgcn_readfirstlane(v)
#define RL(v, l) __builtin_amdgcn_readlane(v, l)

// ---------------- fused prep + scatter (cnt zeroed by hipMemsetAsync) -------
// record (8B): u0 = src(17b) | rel(3b)<<17 | e[0:12)<<20
//              u1 = e[12:21) | (f32(w) & 0xFFFFFE00)

__device__ __forceinline__ void sc1(int e, int src, int dst, int rel, float w,
                                    int* __restrict__ cnt, u64* __restrict__ recs8) {
    unsigned wb = __float_as_uint(w) & 0xFFFFFE00u;
    int slot = atomicAdd(&cnt[dst * CSTR], 1);   // padded: 1 counter per 64B line
    unsigned u0 = (unsigned)src | ((unsigned)rel << 17) | ((unsigned)(e & 0xFFF) << 20);
    unsigned u1 = ((unsigned)e >> 12) | wb;
    recs8[(size_t)dst * CAP + slot] = ((u64)u1 << 32) | u0;   // cached store (no nt)
}

__global__ __launch_bounds__(256) void k_pre(
    const float* __restrict__ x, const int* __restrict__ el,
    const float* __restrict__ wgt,
    const float* __restrict__ W_lin, const float* __restrict__ W_self,
    const float* __restrict__ W_edge, const float* __restrict__ b_edge,
    int* __restrict__ cnt, bf16_t* __restrict__ xb, bf16_t* __restrict__ Bp,
    u64* __restrict__ recs8)
{
    const int t = blockIdx.x * 256 + threadIdx.x;

    // ---- x -> bf16, 16 floats per thread (400000 threads) ----
    if (t < (N_NODES * 64) / 16) {
        const float4* xp = (const float4*)(x + (size_t)t * 16);
        float4 v0 = xp[0], v1 = xp[1], v2 = xp[2], v3 = xp[3];
        bf16x8 o0 = {(bf16_t)v0.x, (bf16_t)v0.y, (bf16_t)v0.z, (bf16_t)v0.w,
                     (bf16_t)v1.x, (bf16_t)v1.y, (bf16_t)v1.z, (bf16_t)v1.w};
        bf16x8 o1 = {(bf16_t)v2.x, (bf16_t)v2.y, (bf16_t)v2.z, (bf16_t)v2.w,
                     (bf16_t)v3.x, (bf16_t)v3.y, (bf16_t)v3.z, (bf16_t)v3.w};
        *(bf16x8*)(xb + (size_t)t * 16)     = o0;
        *(bf16x8*)(xb + (size_t)t * 16 + 8) = o1;
    }

    // ---- pack B (40960 threads) ----
    // B[k][j]: k<448 W_lin[j][k]; 448..511 W_self; 512..623 (W_lin_r@W_edge);
    // 624..630 (W_lin_r@b_edge); 631..639 zero.  Bp[((k/8)*64 + j)*8 + (k%8)]
    if (t < KTOT * 64) {
        int k = t >> 6;
        int j = t & 63;
        float v;
        if (k < 448) {
            v = W_lin[j * 448 + k];
        } else if (k < 512) {
            v = W_self[j * 64 + (k - 448)];
        } else if (k < 624) {
            int r = (k - 512) >> 4, kk = (k - 512) & 15;
            float sacc = 0.f;
            for (int d = 0; d < 64; d++)
                sacc = fmaf(W_lin[j * 448 + r * 64 + d], W_edge[d * 16 + kk], sacc);
            v = sacc;
        } else if (k < 631) {
            int r = k - 624;
            float sacc = 0.f;
            for (int d = 0; d < 64; d++)
                sacc = fmaf(W_lin[j * 448 + r * 64 + d], b_edge[d], sacc);
            v = sacc;
        } else {
            v = 0.f;
        }
        Bp[((k >> 3) * 64 + j) * 8 + (k & 7)] = (bf16_t)v;
    }

    // ---- scatter: 4 edges / thread, int4-coalesced (400000 threads) ----
    if (t < E_EDGES / 4) {
        const int4* ep = (const int4*)(el + (size_t)t * 12);  // t*48B, 16B-aligned
        int4 q0 = ep[0], q1 = ep[1], q2 = ep[2];
        float4 w4 = *(const float4*)(wgt + (size_t)t * 4);
        int e = t * 4;
        sc1(e + 0, q0.x, q0.y, q0.z, w4.x, cnt, recs8);
        sc1(e + 1, q0.w, q1.x, q1.y, w4.y, cnt, recs8);
        sc1(e + 2, q1.z, q1.w, q2.x, w4.z, cnt, recs8);
        sc1(e + 3, q2.y, q2.z, q2.w, w4.w, cnt, recs8);
    }
}

// ---------------- fused gather/segment-sum + MFMA GEMM ----------------------
// block = 256 thr (4 waves) = 16 nodes (round-1 form, measured 138us).
// Per node: one coalesced 8B/lane window load; rel-grouping via __ballot masks
// walked with scalar ctz; records broadcast via readlane; second record-pair
// gated behind a wave-uniform scalar branch; weights decoded with one s_and.

__global__ __launch_bounds__(256) void k_main(
    const bf16_t* __restrict__ xb, const float* __restrict__ ef,
    const float* __restrict__ b_lin, const float* __restrict__ b_self,
    const int* __restrict__ cnt, const u64* __restrict__ recs8,
    const bf16_t* __restrict__ Bp, float* __restrict__ out)
{
    __shared__ __align__(16) bf16_t A[16 * KSTR];  // 20.25 KB, padded stride
    const int wave = threadIdx.x >> 6;
    const int lane = threadIdx.x & 63;
    const int lef  = lane & 15;
    const int nodeBase = blockIdx.x * 16;
    const int n0 = nodeBase + wave * 4;

    // prefetch degrees (strided cnt), windows, self rows for this wave's 4 nodes
    int    md[4];
    u64    rw[4];
    bf16_t sv[4];
#pragma unroll
    for (int i = 0; i < 4; i++) {
        md[i] = cnt[(n0 + i) * CSTR];
        rw[i] = recs8[(size_t)(n0 + i) * CAP + min(lane, CAP - 1)];
        sv[i] = xb[(n0 + i) * 64 + lane];
    }

#pragma unroll
    for (int i = 0; i < 4; i++) {
        const int row = wave * 4 + i;
        bf16_t* Ar = A + row * KSTR;
        Ar[448 + lane] = sv[i];                       // self-term slot
        if (lane < 9) Ar[631 + lane] = (bf16_t)0.f;   // pad cols

        int m = min(md[i], CAP);
        const unsigned u0v = (unsigned)rw[i];
        const unsigned u1v = (unsigned)(rw[i] >> 32);
        const int  relv  = (u0v >> 17) & 7;
        const bool valid = lane < m;

        for (int r = 0; r < R_REL; r++) {
            u64 mr = __ballot(valid && (relv == r));
            float a = 0.f, F = 0.f, s = 0.f;
            while (mr) {
                int i0 = __builtin_ctzll(mr); mr &= mr - 1;
                int i1 = i0; bool two = false, more = false;
                if (mr) { i1 = __builtin_ctzll(mr); mr &= mr - 1;
                          two = true; more = (mr != 0); }
                unsigned a0 = RL(u0v, i0), b0 = RL(u1v, i0);
                unsigned a1 = RL(u0v, i1), b1 = RL(u1v, i1);
                int src0 = a0 & 0x1FFFF, src1 = a1 & 0x1FFFF;
                int e0 = (a0 >> 20) | ((b0 & 0x1FF) << 12);
                int e1 = (a1 >> 20) | ((b1 & 0x1FF) << 12);
                float w0 = __uint_as_float(b0 & 0xFFFFFE00u);
                float w1 = two ? __uint_as_float(b1 & 0xFFFFFE00u) : 0.f;
                float xv0 = (float)xb[src0 * 64 + lane];
                float xv1 = (float)xb[src1 * 64 + lane];
                float ev0 = ef[e0 * EDIM + lef];
                float ev1 = ef[e1 * EDIM + lef];
                if (more) {  // wave-uniform: >=3 records in this group
                    int i2 = __builtin_ctzll(mr); mr &= mr - 1;
                    int i3 = i2; bool four = false;
                    if (mr) { i3 = __builtin_ctzll(mr); mr &= mr - 1; four = true; }
                    unsigned a2 = RL(u0v, i2), b2 = RL(u1v, i2);
                    unsigned a3 = RL(u0v, i3), b3 = RL(u1v, i3);
                    int src2 = a2 & 0x1FFFF, src3 = a3 & 0x1FFFF;
                    int e2 = (a2 >> 20) | ((b2 & 0x1FF) << 12);
                    int e3 = (a3 >> 20) | ((b3 & 0x1FF) << 12);
                    float w2 = __uint_as_float(b2 & 0xFFFFFE00u);
                    float w3 = four ? __uint_as_float(b3 & 0xFFFFFE00u) : 0.f;
                    float xv2 = (float)xb[src2 * 64 + lane];
                    float xv3 = (float)xb[src3 * 64 + lane];
                    float ev2 = ef[e2 * EDIM + lef];
                    float ev3 = ef[e3 * EDIM + lef];
                    a = fmaf(w2, xv2, a); F = fmaf(w2, ev2, F); s += w2;
                    a = fmaf(w3, xv3, a); F = fmaf(w3, ev3, F); s += w3;
                }
                a = fmaf(w0, xv0, a); F = fmaf(w0, ev0, F); s += w0;
                a = fmaf(w1, xv1, a); F = fmaf(w1, ev1, F); s += w1;
            }
            // one flush per relation (covers empty rels with zeros)
            Ar[r * 64 + lane] = (bf16_t)a;
            if (lane < EDIM) Ar[512 + r * EDIM + lane] = (bf16_t)F;
            if (lane == 0)   Ar[624 + r] = (bf16_t)s;
        }
    }
    __syncthreads();

    // stage 2: MFMA over K=640 (A stride padded to KSTR; cols 640..647 unread)
    const int quad = lane >> 4;
    const int l15  = lane & 15;
    f32x4 c = {0.f, 0.f, 0.f, 0.f};
#pragma unroll
    for (int s2i = 0; s2i < KTOT / 32; s2i++) {
        bf16x8 a = *(const bf16x8*)(A + l15 * KSTR + s2i * 32 + quad * 8);
        bf16x8 b = *(const bf16x8*)(Bp + (((s2i * 4 + quad) * 64) + wave * 16 + l15) * 8);
        c = __builtin_amdgcn_mfma_f32_16x16x32_bf16(a, b, c, 0, 0, 0);
    }
    const int j = wave * 16 + l15;
    const float bias = b_lin[j] + b_self[j];
#pragma unroll
    for (int q = 0; q < 4; q++) {
        const int n = nodeBase + quad * 4 + q;
        float v = c[q] + bias;
        out[n * 64 + j] = v > 0.f ? v : 0.f;
    }
}

// ---------------- launch ----------------------------------------------------

extern "C" void kernel_launch(void* const* d_in, const int* in_sizes, int n_in,
                              void* d_out, int out_size, void* d_ws, size_t ws_size,
                              hipStream_t stream) {
    const float* x      = (const float*)d_in[0];
    const int*   el     = (const int*)  d_in[1];
    const float* wgt    = (const float*)d_in[2];
    const float* ef     = (const float*)d_in[3];
    const float* W_lin  = (const float*)d_in[4];
    const float* b_lin  = (const float*)d_in[5];
    const float* W_self = (const float*)d_in[6];
    const float* b_self = (const float*)d_in[7];
    const float* W_edge = (const float*)d_in[8];
    const float* b_edge = (const float*)d_in[9];
    float* out = (float*)d_out;

    // workspace: recs8(44.8M) | cnt(6.4M padded) | xb(12.8M) | Bp(80K) ~64.1 MB
    u64*    recs8 = (u64*)d_ws;
    int*    cnt   = (int*)(recs8 + (size_t)N_NODES * CAP);
    bf16_t* xb    = (bf16_t*)(cnt + (size_t)N_NODES * CSTR);
    bf16_t* Bp    = xb + (size_t)N_NODES * 64;

    hipMemsetAsync(cnt, 0, (size_t)N_NODES * CSTR * sizeof(int), stream);
    k_pre <<<1563, 256, 0, stream>>>(x, el, wgt, W_lin, W_self, W_edge, b_edge,
                                     cnt, xb, Bp, recs8);
    k_main<<<N_NODES / 16, 256, 0, stream>>>(xb, ef, b_lin, b_self,
                                             cnt, recs8, Bp, out);
}